// Round 7
// baseline (268.631 us; speedup 1.0000x reference)
//
#include <hip/hip_runtime.h>
#include <math.h>

#define W 512
#define H 512
#define IMG (W * H)

// ---------------- compile-time operator tables ----------------
// 1D composed second-difference D = diff(diff(.)) from the reference.
// Row i, coefficient of u_j (low-boundary form; high end by mirror symmetry).
__host__ __device__ constexpr double dcoefd(int i, int j) {
    if (i == 0) return j == 0 ? 0.5 : j == 1 ? -1.0 : j == 2 ? 0.5 : 0.0;
    if (i == 1) return j == 0 ? 0.5 : j == 1 ? -0.75 : j == 3 ? 0.25 : 0.0;
    return j == i - 2 ? 0.25 : j == i ? -0.5 : j == i + 2 ? 0.25 : 0.0;
}

// Boundary rows of D, D^2, D^3 for output index 0..5.
struct BTabT {
    float w1[6][16], w2[6][16], w3[6][16];
    constexpr BTabT() : w1{}, w2{}, w3{} {
        for (int i = 0; i < 6; ++i) {
            double r1[20] = {}, r2[20] = {};
            for (int j = 0; j < 20; ++j) r1[j] = dcoefd(i, j);
            for (int j = 0; j < 16; ++j) {
                double s = 0;
                for (int k = 0; k < 18; ++k) s += r1[k] * dcoefd(k, j);
                r2[j] = s;
            }
            for (int j = 0; j < 16; ++j) {
                double s = 0;
                for (int k = 0; k < 16; ++k) s += r2[k] * dcoefd(k, j);
                w3[i][j] = (float)s;
            }
            for (int j = 0; j < 16; ++j) { w1[i][j] = (float)r1[j]; w2[i][j] = (float)r2[j]; }
        }
    }
};
constexpr BTabT BT{};

// Pure (interior) tap of D^a at even offset 2d.
__host__ __device__ constexpr float PT(int a, int d) {
    if (a == 0) return d == 0 ? 1.f : 0.f;
    if (a == 1) return (d == -1 || d == 1) ? 0.25f : d == 0 ? -0.5f : 0.f;
    if (a == 2) return (d == -2 || d == 2) ? 0.0625f
                      : (d == -1 || d == 1) ? -0.25f : d == 0 ? 0.375f : 0.f;
    return (d == -3 || d == 3) ? (1.f/64) : (d == -2 || d == 2) ? (-6.f/64)
         : (d == -1 || d == 1) ? (15.f/64) : d == 0 ? (-20.f/64) : 0.f;
}

// 1D weight of D^b (boundary-aware) at output row Yo, input row r.
__host__ __device__ constexpr float wcoefB(int b, int Yo, int r) {
    if (Yo >= 6 && Yo <= H - 7) {
        const int d = r - Yo;
        if ((d & 1) != 0) return 0.f;
        const int h = d / 2;
        const int ah = h < 0 ? -h : h;
        if (ah > b) return 0.f;
        return PT(b, h);
    }
    const int yi = Yo < 6 ? Yo : (H - 1) - Yo;
    const int jr = Yo < 6 ? r : (H - 1) - r;
    if (jr < 0 || jr > 15) return 0.f;
    return b == 1 ? BT.w1[yi][jr] : b == 2 ? BT.w2[yi][jr] : BT.w3[yi][jr];
}

// Ghost-cell coefficients: u_{-k} = sum_j g[k][j]*u_j makes the PURE stencils
// of D, D^2, D^3 reproduce the boundary-aware operator exactly.
struct GhostT {
    float g[7][8];
    constexpr GhostT() : g{} {
        double v0[8] = {}, v1[8] = {}, v2[8] = {}, w0[8] = {}, w1r[8] = {}, w2r[8] = {};
        for (int j = 0; j < 8; ++j) { v0[j] = dcoefd(0, j); v1[j] = dcoefd(1, j); v2[j] = dcoefd(2, j); }
        for (int j = 0; j < 8; ++j) {
            double s0 = 0, s1 = 0, s2 = 0;
            for (int k = 0; k < 10; ++k) {
                s0 += dcoefd(0, k) * dcoefd(k, j);
                s1 += dcoefd(1, k) * dcoefd(k, j);
                s2 += dcoefd(2, k) * dcoefd(k, j);
            }
            w0[j] = s0; w1r[j] = s1; w2r[j] = s2;
        }
        double um1[8] = {}, um2[8] = {}, um3[8] = {}, um4[8] = {}, um5[8] = {}, um6[8] = {};
        double vm1[8] = {}, vm2[8] = {}, vm3[8] = {}, vm4[8] = {}, wm1[8] = {}, wm2[8] = {};
        for (int j = 0; j < 8; ++j) {
            um1[j] = 2.0 * (j == 0) - (j == 1);
            um2[j] = 4.0 * (j == 0) - 4.0 * (j == 1) + (j == 2);
            vm1[j] = 2 * v0[j] - v1[j];
            vm2[j] = 4 * v0[j] - 4 * v1[j] + v2[j];
            wm1[j] = 2 * w0[j] - w1r[j];
            wm2[j] = 4 * w0[j] - 4 * w1r[j] + w2r[j];
        }
        for (int j = 0; j < 8; ++j) {
            um3[j] = 4 * vm1[j] + 2 * um1[j] - (j == 1);
            um4[j] = 4 * vm2[j] + 2 * um2[j] - (j == 0);
            vm3[j] = 4 * wm1[j] + 2 * vm1[j] - v1[j];
            vm4[j] = 4 * wm2[j] + 2 * vm2[j] - v0[j];
        }
        for (int j = 0; j < 8; ++j) {
            um5[j] = 4 * vm3[j] + 2 * um3[j] - um1[j];
            um6[j] = 4 * vm4[j] + 2 * um4[j] - um2[j];
        }
        for (int j = 0; j < 8; ++j) {
            g[1][j] = (float)um1[j]; g[2][j] = (float)um2[j]; g[3][j] = (float)um3[j];
            g[4][j] = (float)um4[j]; g[5][j] = (float)um5[j]; g[6][j] = (float)um6[j];
        }
    }
};
constexpr GhostT GH{};

// y-weight table for boundary bands: [ly][parity][ri(14)][k(4)][b(4)]
struct WYTabT {
    float w[2][2][14][4][4];
    constexpr WYTabT() : w{} {
        for (int ly = 0; ly < 2; ++ly)
        for (int gg = 0; gg < 2; ++gg)
        for (int ri = 0; ri < 14; ++ri)
        for (int k = 0; k < 4; ++k) {
            const int r  = ly == 0 ? ri : (H - 14) + ri;
            const int Yo = (ly == 0 ? 0 : H - 8) + gg + 2 * k;
            w[ly][gg][ri][k][0] = (r == Yo) ? 1.f : 0.f;
            w[ly][gg][ri][k][1] = wcoefB(1, Yo, r);
            w[ly][gg][ri][k][2] = wcoefB(2, Yo, r);
            w[ly][gg][ri][k][3] = wcoefB(3, Yo, r);
        }
    }
};
__device__ constexpr WYTabT WYT{};

__device__ __forceinline__ float4 ld4(const float* p) {
    return *reinterpret_cast<const float4*>(p);
}
__device__ __forceinline__ float rfl(float x) {
    return __int_as_float(__builtin_amdgcn_readfirstlane(__float_as_int(x)));
}

struct Uni {
    float k1, k2, k3, m1, m2, n1;                               // x-side M consts
    float wy1a, wy1b, wy2a, wy2b, wy2c, wy3a, wy3b, wy3c, wy3d; // interior y-weights
    float sy1, sy2, sy3;                                        // y powers
    float am, iam;                                              // sigmoid mix, 1/am
};

// Ghost-patch for the 4 edge slots (c in {0,1,126,127}); depth D = 2*CLS.
// rb[8..11] = cols gx0..gx0+3; c==1/126 only need patching at D==6.
template<int D>
__device__ __forceinline__ void patch4(float rb[20], int c) {
    if (c == 0) {
        #pragma unroll
        for (int k = 1; k <= D; ++k) {
            float a = 0.f;
            #pragma unroll
            for (int j = 0; j < 8; ++j) {
                const float w = GH.g[k][j];
                if (w != 0.f) a = fmaf(w, rb[8 + j], a);
            }
            rb[8 - k] = a;
        }
    } else if (D >= 6 && c == 1) {
        #pragma unroll
        for (int k = 1; k <= 2; ++k) {
            float a = 0.f;
            #pragma unroll
            for (int j = 0; j < 8; ++j) {
                const float w = GH.g[k][j];
                if (w != 0.f) a = fmaf(w, rb[4 + j], a);
            }
            rb[4 - k] = a;
        }
    } else if (D >= 6 && c == 126) {
        #pragma unroll
        for (int k = 1; k <= 2; ++k) {
            float a = 0.f;
            #pragma unroll
            for (int j = 0; j < 8; ++j) {
                const float w = GH.g[k][j];
                if (w != 0.f) a = fmaf(w, rb[15 - j], a);
            }
            rb[15 + k] = a;
        }
    } else if (c == 127) {
        #pragma unroll
        for (int k = 1; k <= D; ++k) {
            float a = 0.f;
            #pragma unroll
            for (int j = 0; j < 8; ++j) {
                const float w = GH.g[k][j];
                if (w != 0.f) a = fmaf(w, rb[11 - j], a);
            }
            rb[11 + k] = a;
        }
    }
}

// One trimmed pure-y row. CLS = max x-derivative order needed by this row.
template<int CLS, int RI>
__device__ __forceinline__ void row_pure(const Uni& U, const float* __restrict__ p,
                                         int yb0, const int colm[5], int c,
                                         float acc[4][4]) {
    const int r = yb0 - 6 + 2 * RI;
    const float* row = p + (size_t)r * W;
    float rb[20];
    if (CLS == 0) {
        *reinterpret_cast<float4*>(&rb[8]) = ld4(row + colm[2]);
    } else if (CLS <= 2) {
        *reinterpret_cast<float4*>(&rb[4])  = ld4(row + colm[1]);
        *reinterpret_cast<float4*>(&rb[8])  = ld4(row + colm[2]);
        *reinterpret_cast<float4*>(&rb[12]) = ld4(row + colm[3]);
    } else {
        #pragma unroll
        for (int m = 0; m < 5; ++m)
            *reinterpret_cast<float4*>(&rb[4 * m]) = ld4(row + colm[m]);
    }
    if (CLS >= 1) patch4<2 * CLS>(rb, c);

    #pragma unroll
    for (int j = 0; j < 4; ++j) {
        const float u0 = rb[8 + j];
        const float M3v = 120.f * u0;
        float M2v = 0.f, M1v = 0.f, M0v = 0.f;
        if (CLS >= 1) {
            const float p1 = rb[6 + j] + rb[10 + j];
            const float X1 = fmaf(0.25f, p1, -0.5f * u0);
            M2v = fmaf(U.n1, X1, 45.f * u0);
            if (CLS >= 2) {
                const float p2 = rb[4 + j] + rb[12 + j];
                const float X2 = fmaf(0.0625f, p2, fmaf(-0.25f, p1, 0.375f * u0));
                M1v = fmaf(U.m1, X1, fmaf(U.m2, X2, 10.f * u0));
                if (CLS >= 3) {
                    const float p3 = rb[2 + j] + rb[14 + j];
                    const float X3 = fmaf(1.f/64, p3, fmaf(-6.f/64, p2,
                                      fmaf(15.f/64, p1, (-20.f/64) * u0)));
                    M0v = fmaf(U.k1, X1, fmaf(U.k2, X2, U.k3 * X3));
                }
            }
        }
        #pragma unroll
        for (int k = 0; k < 4; ++k) {
            const int dq = RI - 3 - k;
            const int ad = dq < 0 ? -dq : dq;
            if (ad > 3) continue;
            float a = acc[k][j];
            if (ad == 0) {
                a = fmaf(U.iam, u0, a);       // fold u/am into acc
                a += M0v;
                a = fmaf(U.wy1b, M1v, a);
                a = fmaf(U.wy2c, M2v, a);
                a = fmaf(U.wy3d, M3v, a);
            } else if (ad == 1) {
                a = fmaf(U.wy1a, M1v, a);
                a = fmaf(U.wy2b, M2v, a);
                a = fmaf(U.wy3c, M3v, a);
            } else if (ad == 2) {
                a = fmaf(U.wy2a, M2v, a);
                a = fmaf(U.wy3b, M3v, a);
            } else {
                a = fmaf(U.wy3a, M3v, a);
            }
            acc[k][j] = a;
        }
    }
}

__global__ __launch_bounds__(256, 5) void fused_v7(
        const float* __restrict__ uin, float* __restrict__ outp,
        const float* __restrict__ alpha, const float* __restrict__ beta,
        const float* __restrict__ axp, const float* __restrict__ ayp,
        const float* __restrict__ es) {
    // XCD-chunked swizzle (grid 4096 = 8*512)
    const unsigned bid = blockIdx.x;
    const unsigned swz = (bid & 7u) * (gridDim.x >> 3) + (bid >> 3);
    const unsigned img  = swz >> 6;          // 64 bands of 8 rows per image
    const unsigned band = swz & 63u;

    const float* __restrict__ p = uin + (size_t)img * IMG;
    float* __restrict__ q = outp + (size_t)img * IMG;

    const float sx = 0.01f * alpha[0] * axp[0];
    const float sy = 0.01f * beta[0]  * ayp[0];
    Uni U;
    U.k1 = rfl(10.f * sx);  U.k2 = rfl(45.f * sx * sx);  U.k3 = rfl(120.f * sx * sx * sx);
    U.m1 = rfl(90.f * sx);  U.m2 = rfl(360.f * sx * sx); U.n1 = rfl(360.f * sx);
    const float sy2 = sy * sy, sy3 = sy2 * sy;
    U.sy1 = rfl(sy); U.sy2 = rfl(sy2); U.sy3 = rfl(sy3);
    U.wy1a = rfl(0.25f * sy);    U.wy1b = rfl(-0.5f * sy);
    U.wy2a = rfl(0.0625f * sy2); U.wy2b = rfl(-0.25f * sy2); U.wy2c = rfl(0.375f * sy2);
    U.wy3a = rfl((1.f/64) * sy3);  U.wy3b = rfl((-6.f/64) * sy3);
    U.wy3c = rfl((15.f/64) * sy3); U.wy3d = rfl((-20.f/64) * sy3);
    const float amv = 1.f / (1.f + expf(-es[0]));
    U.am = rfl(amv); U.iam = rfl(1.f / amv);

    const int tid = threadIdx.x;
    const int g = tid >> 7;                      // parity group (2 per block)
    const int c = ((tid & 127) + 2) & 127;       // rotate: edges cluster in odd waves
    const int gx0 = c << 2;

    int colm[5];
    #pragma unroll
    for (int m = 0; m < 5; ++m) {
        int cc = gx0 - 8 + 4 * m;
        colm[m] = cc < 0 ? 0 : (cc > W - 4 ? W - 4 : cc);
    }

    const int y0 = (int)band << 3;
    const int yb0 = y0 + g;                      // outputs at yb0 + 2k
    const bool ytab = (band == 0) || (band == 63);

    float acc[4][4] = {};

    if (!ytab) {
        // ---------- hot path: pure y, class-trimmed rows ----------
        row_pure<0, 0>(U, p, yb0, colm, c, acc);
        row_pure<1, 1>(U, p, yb0, colm, c, acc);
        row_pure<2, 2>(U, p, yb0, colm, c, acc);
        row_pure<3, 3>(U, p, yb0, colm, c, acc);
        row_pure<3, 4>(U, p, yb0, colm, c, acc);
        row_pure<3, 5>(U, p, yb0, colm, c, acc);
        row_pure<3, 6>(U, p, yb0, colm, c, acc);
        row_pure<2, 7>(U, p, yb0, colm, c, acc);
        row_pure<1, 8>(U, p, yb0, colm, c, acc);
        row_pure<0, 9>(U, p, yb0, colm, c, acc);
    } else {
        // ---------- y-boundary bands 0/63 (block-uniform): table path ----------
        const int ly = (band == 0) ? 0 : 1;
        #pragma unroll 1
        for (int ri = 0; ri < 14; ++ri) {
            const int r = ly ? (H - 14) + ri : ri;
            const float* row = p + (size_t)r * W;
            float rb[20];
            #pragma unroll
            for (int m = 0; m < 5; ++m)
                *reinterpret_cast<float4*>(&rb[4 * m]) = ld4(row + colm[m]);
            patch4<6>(rb, c);
            float M0v[4], M1v[4], M2v[4], M3v[4];
            #pragma unroll
            for (int j = 0; j < 4; ++j) {
                const float u0 = rb[8 + j];
                const float p1 = rb[6 + j] + rb[10 + j];
                const float p2 = rb[4 + j] + rb[12 + j];
                const float p3 = rb[2 + j] + rb[14 + j];
                const float X1 = fmaf(0.25f, p1, -0.5f * u0);
                const float X2 = fmaf(0.0625f, p2, fmaf(-0.25f, p1, 0.375f * u0));
                const float X3 = fmaf(1.f/64, p3, fmaf(-6.f/64, p2,
                                  fmaf(15.f/64, p1, (-20.f/64) * u0)));
                // fold u/am into the w0 (r==Yo) term
                M0v[j] = fmaf(U.k1, X1, fmaf(U.k2, X2, fmaf(U.k3, X3, U.iam * u0)));
                M1v[j] = fmaf(U.m1, X1, fmaf(U.m2, X2, 10.f * u0));
                M2v[j] = fmaf(U.n1, X1, 45.f * u0);
                M3v[j] = 120.f * u0;
            }
            #pragma unroll
            for (int k = 0; k < 4; ++k) {
                const float* wr = &WYT.w[ly][g][ri][k][0];
                const float w0 = wr[0];
                const float w1 = wr[1] * U.sy1;
                const float w2 = wr[2] * U.sy2;
                const float w3 = wr[3] * U.sy3;
                #pragma unroll
                for (int j = 0; j < 4; ++j)
                    acc[k][j] = fmaf(w0, M0v[j], fmaf(w1, M1v[j],
                                 fmaf(w2, M2v[j], fmaf(w3, M3v[j], acc[k][j]))));
            }
        }
    }

    // ---- out = am * acc   (acc already contains u/am at the dq==0 row) ----
    #pragma unroll
    for (int k = 0; k < 4; ++k) {
        const int Yo = yb0 + 2 * k;
        float4 o;
        o.x = U.am * acc[k][0];
        o.y = U.am * acc[k][1];
        o.z = U.am * acc[k][2];
        o.w = U.am * acc[k][3];
        *reinterpret_cast<float4*>(q + (size_t)Yo * W + gx0) = o;
    }
}

extern "C" void kernel_launch(void* const* d_in, const int* in_sizes, int n_in,
                              void* d_out, int out_size, void* d_ws, size_t ws_size,
                              hipStream_t stream) {
    const float* u     = (const float*)d_in[0];
    const float* alpha = (const float*)d_in[1];
    const float* beta  = (const float*)d_in[2];
    const float* ax    = (const float*)d_in[3];
    const float* ay    = (const float*)d_in[4];
    const float* es    = (const float*)d_in[5];
    float* out = (float*)d_out;

    int nimg = in_sizes[0] / IMG;            // 64 images
    dim3 block(256);
    dim3 grid((unsigned)(nimg * 64));        // 64 bands (8 rows) per image
    fused_v7<<<grid, block, 0, stream>>>(u, out, alpha, beta, ax, ay, es);
}

// Round 8
// 152.980 us; speedup vs baseline: 1.7560x; 1.7560x over previous
//
#include <hip/hip_runtime.h>
#include <math.h>

#define W 512
#define H 512
#define IMG (W * H)

// ---------------- compile-time operator tables ----------------
// 1D composed second-difference D = diff(diff(.)) from the reference.
// Row i, coefficient of u_j (low-boundary form; high end by mirror symmetry).
__host__ __device__ constexpr double dcoefd(int i, int j) {
    if (i == 0) return j == 0 ? 0.5 : j == 1 ? -1.0 : j == 2 ? 0.5 : 0.0;
    if (i == 1) return j == 0 ? 0.5 : j == 1 ? -0.75 : j == 3 ? 0.25 : 0.0;
    return j == i - 2 ? 0.25 : j == i ? -0.5 : j == i + 2 ? 0.25 : 0.0;
}

// Boundary rows of D, D^2, D^3 for output index 0..5.
struct BTabT {
    float w1[6][16], w2[6][16], w3[6][16];
    constexpr BTabT() : w1{}, w2{}, w3{} {
        for (int i = 0; i < 6; ++i) {
            double r1[20] = {}, r2[20] = {};
            for (int j = 0; j < 20; ++j) r1[j] = dcoefd(i, j);
            for (int j = 0; j < 16; ++j) {
                double s = 0;
                for (int k = 0; k < 18; ++k) s += r1[k] * dcoefd(k, j);
                r2[j] = s;
            }
            for (int j = 0; j < 16; ++j) {
                double s = 0;
                for (int k = 0; k < 16; ++k) s += r2[k] * dcoefd(k, j);
                w3[i][j] = (float)s;
            }
            for (int j = 0; j < 16; ++j) { w1[i][j] = (float)r1[j]; w2[i][j] = (float)r2[j]; }
        }
    }
};
constexpr BTabT BT{};

// Pure (interior) tap of D^a at even offset 2d.
__host__ __device__ constexpr float PT(int a, int d) {
    if (a == 0) return d == 0 ? 1.f : 0.f;
    if (a == 1) return (d == -1 || d == 1) ? 0.25f : d == 0 ? -0.5f : 0.f;
    if (a == 2) return (d == -2 || d == 2) ? 0.0625f
                      : (d == -1 || d == 1) ? -0.25f : d == 0 ? 0.375f : 0.f;
    return (d == -3 || d == 3) ? (1.f/64) : (d == -2 || d == 2) ? (-6.f/64)
         : (d == -1 || d == 1) ? (15.f/64) : d == 0 ? (-20.f/64) : 0.f;
}

// 1D weight of D^b (boundary-aware) at output row Yo, input row r.
__host__ __device__ constexpr float wcoefB(int b, int Yo, int r) {
    if (Yo >= 6 && Yo <= H - 7) {
        const int d = r - Yo;
        if ((d & 1) != 0) return 0.f;
        const int h = d / 2;
        const int ah = h < 0 ? -h : h;
        if (ah > b) return 0.f;
        return PT(b, h);
    }
    const int yi = Yo < 6 ? Yo : (H - 1) - Yo;
    const int jr = Yo < 6 ? r : (H - 1) - r;
    if (jr < 0 || jr > 15) return 0.f;
    return b == 1 ? BT.w1[yi][jr] : b == 2 ? BT.w2[yi][jr] : BT.w3[yi][jr];
}

// Ghost-cell coefficients: u_{-k} = sum_j g[k][j]*u_j makes the PURE stencils
// of D, D^2, D^3 reproduce the boundary-aware operator exactly.
struct GhostT {
    float g[7][8];
    constexpr GhostT() : g{} {
        double v0[8] = {}, v1[8] = {}, v2[8] = {}, w0[8] = {}, w1r[8] = {}, w2r[8] = {};
        for (int j = 0; j < 8; ++j) { v0[j] = dcoefd(0, j); v1[j] = dcoefd(1, j); v2[j] = dcoefd(2, j); }
        for (int j = 0; j < 8; ++j) {
            double s0 = 0, s1 = 0, s2 = 0;
            for (int k = 0; k < 10; ++k) {
                s0 += dcoefd(0, k) * dcoefd(k, j);
                s1 += dcoefd(1, k) * dcoefd(k, j);
                s2 += dcoefd(2, k) * dcoefd(k, j);
            }
            w0[j] = s0; w1r[j] = s1; w2r[j] = s2;
        }
        double um1[8] = {}, um2[8] = {}, um3[8] = {}, um4[8] = {}, um5[8] = {}, um6[8] = {};
        double vm1[8] = {}, vm2[8] = {}, vm3[8] = {}, vm4[8] = {}, wm1[8] = {}, wm2[8] = {};
        for (int j = 0; j < 8; ++j) {
            um1[j] = 2.0 * (j == 0) - (j == 1);
            um2[j] = 4.0 * (j == 0) - 4.0 * (j == 1) + (j == 2);
            vm1[j] = 2 * v0[j] - v1[j];
            vm2[j] = 4 * v0[j] - 4 * v1[j] + v2[j];
            wm1[j] = 2 * w0[j] - w1r[j];
            wm2[j] = 4 * w0[j] - 4 * w1r[j] + w2r[j];
        }
        for (int j = 0; j < 8; ++j) {
            um3[j] = 4 * vm1[j] + 2 * um1[j] - (j == 1);
            um4[j] = 4 * vm2[j] + 2 * um2[j] - (j == 0);
            vm3[j] = 4 * wm1[j] + 2 * vm1[j] - v1[j];
            vm4[j] = 4 * wm2[j] + 2 * vm2[j] - v0[j];
        }
        for (int j = 0; j < 8; ++j) {
            um5[j] = 4 * vm3[j] + 2 * um3[j] - um1[j];
            um6[j] = 4 * vm4[j] + 2 * um4[j] - um2[j];
        }
        for (int j = 0; j < 8; ++j) {
            g[1][j] = (float)um1[j]; g[2][j] = (float)um2[j]; g[3][j] = (float)um3[j];
            g[4][j] = (float)um4[j]; g[5][j] = (float)um5[j]; g[6][j] = (float)um6[j];
        }
    }
};
constexpr GhostT GH{};

// y-weight table for boundary bands: [ly][parity][ri(14)][k(4)][b(4)]
struct WYTabT {
    float w[2][2][14][4][4];
    constexpr WYTabT() : w{} {
        for (int ly = 0; ly < 2; ++ly)
        for (int gg = 0; gg < 2; ++gg)
        for (int ri = 0; ri < 14; ++ri)
        for (int k = 0; k < 4; ++k) {
            const int r  = ly == 0 ? ri : (H - 14) + ri;
            const int Yo = (ly == 0 ? 0 : H - 8) + gg + 2 * k;
            w[ly][gg][ri][k][0] = (r == Yo) ? 1.f : 0.f;
            w[ly][gg][ri][k][1] = wcoefB(1, Yo, r);
            w[ly][gg][ri][k][2] = wcoefB(2, Yo, r);
            w[ly][gg][ri][k][3] = wcoefB(3, Yo, r);
        }
    }
};
__device__ constexpr WYTabT WYT{};

__device__ __forceinline__ float4 ld4(const float* p) {
    return *reinterpret_cast<const float4*>(p);
}
__device__ __forceinline__ float rfl(float x) {
    return __int_as_float(__builtin_amdgcn_readfirstlane(__float_as_int(x)));
}

struct Uni {
    float k1, k2, k3, m1, m2, n1;                               // x-side M consts
    float wy1a, wy1b, wy2a, wy2b, wy2c, wy3a, wy3b, wy3c, wy3d; // interior y-weights
    float sy1, sy2, sy3;                                        // y powers
    float am, iam;                                              // sigmoid mix, 1/am
};

// Ghost-patch for the 4 edge slots (c in {0,1,126,127}); depth D = 2*CLS.
// rb[8..11] = cols gx0..gx0+3; c==1/126 only need patching at D==6.
template<int D>
__device__ __forceinline__ void patch4(float rb[20], int c) {
    if (c == 0) {
        #pragma unroll
        for (int k = 1; k <= D; ++k) {
            float a = 0.f;
            #pragma unroll
            for (int j = 0; j < 8; ++j) {
                const float w = GH.g[k][j];
                if (w != 0.f) a = fmaf(w, rb[8 + j], a);
            }
            rb[8 - k] = a;
        }
    } else if (D >= 6 && c == 1) {
        #pragma unroll
        for (int k = 1; k <= 2; ++k) {
            float a = 0.f;
            #pragma unroll
            for (int j = 0; j < 8; ++j) {
                const float w = GH.g[k][j];
                if (w != 0.f) a = fmaf(w, rb[4 + j], a);
            }
            rb[4 - k] = a;
        }
    } else if (D >= 6 && c == 126) {
        #pragma unroll
        for (int k = 1; k <= 2; ++k) {
            float a = 0.f;
            #pragma unroll
            for (int j = 0; j < 8; ++j) {
                const float w = GH.g[k][j];
                if (w != 0.f) a = fmaf(w, rb[15 - j], a);
            }
            rb[15 + k] = a;
        }
    } else if (c == 127) {
        #pragma unroll
        for (int k = 1; k <= D; ++k) {
            float a = 0.f;
            #pragma unroll
            for (int j = 0; j < 8; ++j) {
                const float w = GH.g[k][j];
                if (w != 0.f) a = fmaf(w, rb[11 - j], a);
            }
            rb[11 + k] = a;
        }
    }
}

// One trimmed pure-y row. CLS = max x-derivative order needed by this row.
template<int CLS, int RI>
__device__ __forceinline__ void row_pure(const Uni& U, const float* __restrict__ p,
                                         int yb0, const int colm[5], int c,
                                         float acc[4][4]) {
    const int r = yb0 - 6 + 2 * RI;
    const float* row = p + (size_t)r * W;
    float rb[20];
    if (CLS == 0) {
        *reinterpret_cast<float4*>(&rb[8]) = ld4(row + colm[2]);
    } else if (CLS <= 2) {
        *reinterpret_cast<float4*>(&rb[4])  = ld4(row + colm[1]);
        *reinterpret_cast<float4*>(&rb[8])  = ld4(row + colm[2]);
        *reinterpret_cast<float4*>(&rb[12]) = ld4(row + colm[3]);
    } else {
        #pragma unroll
        for (int m = 0; m < 5; ++m)
            *reinterpret_cast<float4*>(&rb[4 * m]) = ld4(row + colm[m]);
    }
    if (CLS >= 1) patch4<2 * CLS>(rb, c);

    #pragma unroll
    for (int j = 0; j < 4; ++j) {
        const float u0 = rb[8 + j];
        const float M3v = 120.f * u0;
        float M2v = 0.f, M1v = 0.f, M0v = 0.f;
        if (CLS >= 1) {
            const float p1 = rb[6 + j] + rb[10 + j];
            const float X1 = fmaf(0.25f, p1, -0.5f * u0);
            M2v = fmaf(U.n1, X1, 45.f * u0);
            if (CLS >= 2) {
                const float p2 = rb[4 + j] + rb[12 + j];
                const float X2 = fmaf(0.0625f, p2, fmaf(-0.25f, p1, 0.375f * u0));
                M1v = fmaf(U.m1, X1, fmaf(U.m2, X2, 10.f * u0));
                if (CLS >= 3) {
                    const float p3 = rb[2 + j] + rb[14 + j];
                    const float X3 = fmaf(1.f/64, p3, fmaf(-6.f/64, p2,
                                      fmaf(15.f/64, p1, (-20.f/64) * u0)));
                    M0v = fmaf(U.k1, X1, fmaf(U.k2, X2, U.k3 * X3));
                }
            }
        }
        #pragma unroll
        for (int k = 0; k < 4; ++k) {
            const int dq = RI - 3 - k;
            const int ad = dq < 0 ? -dq : dq;
            if (ad > 3) continue;
            float a = acc[k][j];
            if (ad == 0) {
                a = fmaf(U.iam, u0, a);       // fold u/am into acc
                a += M0v;
                a = fmaf(U.wy1b, M1v, a);
                a = fmaf(U.wy2c, M2v, a);
                a = fmaf(U.wy3d, M3v, a);
            } else if (ad == 1) {
                a = fmaf(U.wy1a, M1v, a);
                a = fmaf(U.wy2b, M2v, a);
                a = fmaf(U.wy3c, M3v, a);
            } else if (ad == 2) {
                a = fmaf(U.wy2a, M2v, a);
                a = fmaf(U.wy3b, M3v, a);
            } else {
                a = fmaf(U.wy3a, M3v, a);
            }
            acc[k][j] = a;
        }
    }
}

__global__ __launch_bounds__(256, 4) void fused_v8(
        const float* __restrict__ uin, float* __restrict__ outp,
        const float* __restrict__ alpha, const float* __restrict__ beta,
        const float* __restrict__ axp, const float* __restrict__ ayp,
        const float* __restrict__ es) {
    // XCD-chunked swizzle (grid 4096 = 8*512)
    const unsigned bid = blockIdx.x;
    const unsigned swz = (bid & 7u) * (gridDim.x >> 3) + (bid >> 3);
    const unsigned img  = swz >> 6;          // 64 bands of 8 rows per image
    const unsigned band = swz & 63u;

    const float* __restrict__ p = uin + (size_t)img * IMG;
    float* __restrict__ q = outp + (size_t)img * IMG;

    const float sx = 0.01f * alpha[0] * axp[0];
    const float sy = 0.01f * beta[0]  * ayp[0];
    Uni U;
    U.k1 = rfl(10.f * sx);  U.k2 = rfl(45.f * sx * sx);  U.k3 = rfl(120.f * sx * sx * sx);
    U.m1 = rfl(90.f * sx);  U.m2 = rfl(360.f * sx * sx); U.n1 = rfl(360.f * sx);
    const float sy2 = sy * sy, sy3 = sy2 * sy;
    U.sy1 = rfl(sy); U.sy2 = rfl(sy2); U.sy3 = rfl(sy3);
    U.wy1a = rfl(0.25f * sy);    U.wy1b = rfl(-0.5f * sy);
    U.wy2a = rfl(0.0625f * sy2); U.wy2b = rfl(-0.25f * sy2); U.wy2c = rfl(0.375f * sy2);
    U.wy3a = rfl((1.f/64) * sy3);  U.wy3b = rfl((-6.f/64) * sy3);
    U.wy3c = rfl((15.f/64) * sy3); U.wy3d = rfl((-20.f/64) * sy3);
    const float amv = 1.f / (1.f + expf(-es[0]));
    U.am = rfl(amv); U.iam = rfl(1.f / amv);

    const int tid = threadIdx.x;
    const int g = tid >> 7;                      // parity group (2 per block)
    const int c = ((tid & 127) + 2) & 127;       // rotate: edges cluster in odd waves
    const int gx0 = c << 2;

    int colm[5];
    #pragma unroll
    for (int m = 0; m < 5; ++m) {
        int cc = gx0 - 8 + 4 * m;
        colm[m] = cc < 0 ? 0 : (cc > W - 4 ? W - 4 : cc);
    }

    const int y0 = (int)band << 3;
    const int yb0 = y0 + g;                      // outputs at yb0 + 2k
    const bool ytab = (band == 0) || (band == 63);

    float acc[4][4] = {};

    if (!ytab) {
        // ---------- hot path: pure y, class-trimmed rows ----------
        row_pure<0, 0>(U, p, yb0, colm, c, acc);
        row_pure<1, 1>(U, p, yb0, colm, c, acc);
        row_pure<2, 2>(U, p, yb0, colm, c, acc);
        row_pure<3, 3>(U, p, yb0, colm, c, acc);
        row_pure<3, 4>(U, p, yb0, colm, c, acc);
        row_pure<3, 5>(U, p, yb0, colm, c, acc);
        row_pure<3, 6>(U, p, yb0, colm, c, acc);
        row_pure<2, 7>(U, p, yb0, colm, c, acc);
        row_pure<1, 8>(U, p, yb0, colm, c, acc);
        row_pure<0, 9>(U, p, yb0, colm, c, acc);
    } else {
        // ---------- y-boundary bands 0/63 (block-uniform): table path ----------
        const int ly = (band == 0) ? 0 : 1;
        #pragma unroll 1
        for (int ri = 0; ri < 14; ++ri) {
            const int r = ly ? (H - 14) + ri : ri;
            const float* row = p + (size_t)r * W;
            float rb[20];
            #pragma unroll
            for (int m = 0; m < 5; ++m)
                *reinterpret_cast<float4*>(&rb[4 * m]) = ld4(row + colm[m]);
            patch4<6>(rb, c);
            float M0v[4], M1v[4], M2v[4], M3v[4];
            #pragma unroll
            for (int j = 0; j < 4; ++j) {
                const float u0 = rb[8 + j];
                const float p1 = rb[6 + j] + rb[10 + j];
                const float p2 = rb[4 + j] + rb[12 + j];
                const float p3 = rb[2 + j] + rb[14 + j];
                const float X1 = fmaf(0.25f, p1, -0.5f * u0);
                const float X2 = fmaf(0.0625f, p2, fmaf(-0.25f, p1, 0.375f * u0));
                const float X3 = fmaf(1.f/64, p3, fmaf(-6.f/64, p2,
                                  fmaf(15.f/64, p1, (-20.f/64) * u0)));
                // fold u/am into the w0 (r==Yo) term
                M0v[j] = fmaf(U.k1, X1, fmaf(U.k2, X2, fmaf(U.k3, X3, U.iam * u0)));
                M1v[j] = fmaf(U.m1, X1, fmaf(U.m2, X2, 10.f * u0));
                M2v[j] = fmaf(U.n1, X1, 45.f * u0);
                M3v[j] = 120.f * u0;
            }
            #pragma unroll
            for (int k = 0; k < 4; ++k) {
                const float* wr = &WYT.w[ly][g][ri][k][0];
                const float w0 = wr[0];
                const float w1 = wr[1] * U.sy1;
                const float w2 = wr[2] * U.sy2;
                const float w3 = wr[3] * U.sy3;
                #pragma unroll
                for (int j = 0; j < 4; ++j)
                    acc[k][j] = fmaf(w0, M0v[j], fmaf(w1, M1v[j],
                                 fmaf(w2, M2v[j], fmaf(w3, M3v[j], acc[k][j]))));
            }
        }
    }

    // ---- out = am * acc   (acc already contains u/am at the dq==0 row) ----
    #pragma unroll
    for (int k = 0; k < 4; ++k) {
        const int Yo = yb0 + 2 * k;
        float4 o;
        o.x = U.am * acc[k][0];
        o.y = U.am * acc[k][1];
        o.z = U.am * acc[k][2];
        o.w = U.am * acc[k][3];
        *reinterpret_cast<float4*>(q + (size_t)Yo * W + gx0) = o;
    }
}

extern "C" void kernel_launch(void* const* d_in, const int* in_sizes, int n_in,
                              void* d_out, int out_size, void* d_ws, size_t ws_size,
                              hipStream_t stream) {
    const float* u     = (const float*)d_in[0];
    const float* alpha = (const float*)d_in[1];
    const float* beta  = (const float*)d_in[2];
    const float* ax    = (const float*)d_in[3];
    const float* ay    = (const float*)d_in[4];
    const float* es    = (const float*)d_in[5];
    float* out = (float*)d_out;

    int nimg = in_sizes[0] / IMG;            // 64 images
    dim3 block(256);
    dim3 grid((unsigned)(nimg * 64));        // 64 bands (8 rows) per image
    fused_v8<<<grid, block, 0, stream>>>(u, out, alpha, beta, ax, ay, es);
}

// Round 9
// 75.997 us; speedup vs baseline: 3.5347x; 2.0130x over previous
//
#include <hip/hip_runtime.h>
#include <math.h>

#define W 512
#define H 512
#define IMG (W * H)

// ---------------- compile-time operator tables ----------------
// 1D composed second-difference D = diff(diff(.)) from the reference.
// Row i, coefficient of u_j (low-boundary form; high end by mirror symmetry).
__host__ __device__ constexpr double dcoefd(int i, int j) {
    if (i == 0) return j == 0 ? 0.5 : j == 1 ? -1.0 : j == 2 ? 0.5 : 0.0;
    if (i == 1) return j == 0 ? 0.5 : j == 1 ? -0.75 : j == 3 ? 0.25 : 0.0;
    return j == i - 2 ? 0.25 : j == i ? -0.5 : j == i + 2 ? 0.25 : 0.0;
}

// Boundary rows of D, D^2, D^3 for output index 0..5.
struct BTabT {
    float w1[6][16], w2[6][16], w3[6][16];
    constexpr BTabT() : w1{}, w2{}, w3{} {
        for (int i = 0; i < 6; ++i) {
            double r1[20] = {}, r2[20] = {};
            for (int j = 0; j < 20; ++j) r1[j] = dcoefd(i, j);
            for (int j = 0; j < 16; ++j) {
                double s = 0;
                for (int k = 0; k < 18; ++k) s += r1[k] * dcoefd(k, j);
                r2[j] = s;
            }
            for (int j = 0; j < 16; ++j) {
                double s = 0;
                for (int k = 0; k < 16; ++k) s += r2[k] * dcoefd(k, j);
                w3[i][j] = (float)s;
            }
            for (int j = 0; j < 16; ++j) { w1[i][j] = (float)r1[j]; w2[i][j] = (float)r2[j]; }
        }
    }
};
constexpr BTabT BT{};

// Pure (interior) tap of D^a at even offset 2d.
__host__ __device__ constexpr float PT(int a, int d) {
    if (a == 0) return d == 0 ? 1.f : 0.f;
    if (a == 1) return (d == -1 || d == 1) ? 0.25f : d == 0 ? -0.5f : 0.f;
    if (a == 2) return (d == -2 || d == 2) ? 0.0625f
                      : (d == -1 || d == 1) ? -0.25f : d == 0 ? 0.375f : 0.f;
    return (d == -3 || d == 3) ? (1.f/64) : (d == -2 || d == 2) ? (-6.f/64)
         : (d == -1 || d == 1) ? (15.f/64) : d == 0 ? (-20.f/64) : 0.f;
}

// 1D weight of D^b (boundary-aware) at output row Yo, input row r.
__host__ __device__ constexpr float wcoefB(int b, int Yo, int r) {
    if (Yo >= 6 && Yo <= H - 7) {
        const int d = r - Yo;
        if ((d & 1) != 0) return 0.f;
        const int h = d / 2;
        const int ah = h < 0 ? -h : h;
        if (ah > b) return 0.f;
        return PT(b, h);
    }
    const int yi = Yo < 6 ? Yo : (H - 1) - Yo;
    const int jr = Yo < 6 ? r : (H - 1) - r;
    if (jr < 0 || jr > 15) return 0.f;
    return b == 1 ? BT.w1[yi][jr] : b == 2 ? BT.w2[yi][jr] : BT.w3[yi][jr];
}

// Ghost-cell coefficients: u_{-k} = sum_j g[k][j]*u_j makes the PURE stencils
// of D, D^2, D^3 reproduce the boundary-aware operator exactly.
struct GhostT {
    float g[7][8];
    constexpr GhostT() : g{} {
        double v0[8] = {}, v1[8] = {}, v2[8] = {}, w0[8] = {}, w1r[8] = {}, w2r[8] = {};
        for (int j = 0; j < 8; ++j) { v0[j] = dcoefd(0, j); v1[j] = dcoefd(1, j); v2[j] = dcoefd(2, j); }
        for (int j = 0; j < 8; ++j) {
            double s0 = 0, s1 = 0, s2 = 0;
            for (int k = 0; k < 10; ++k) {
                s0 += dcoefd(0, k) * dcoefd(k, j);
                s1 += dcoefd(1, k) * dcoefd(k, j);
                s2 += dcoefd(2, k) * dcoefd(k, j);
            }
            w0[j] = s0; w1r[j] = s1; w2r[j] = s2;
        }
        double um1[8] = {}, um2[8] = {}, um3[8] = {}, um4[8] = {}, um5[8] = {}, um6[8] = {};
        double vm1[8] = {}, vm2[8] = {}, vm3[8] = {}, vm4[8] = {}, wm1[8] = {}, wm2[8] = {};
        for (int j = 0; j < 8; ++j) {
            um1[j] = 2.0 * (j == 0) - (j == 1);
            um2[j] = 4.0 * (j == 0) - 4.0 * (j == 1) + (j == 2);
            vm1[j] = 2 * v0[j] - v1[j];
            vm2[j] = 4 * v0[j] - 4 * v1[j] + v2[j];
            wm1[j] = 2 * w0[j] - w1r[j];
            wm2[j] = 4 * w0[j] - 4 * w1r[j] + w2r[j];
        }
        for (int j = 0; j < 8; ++j) {
            um3[j] = 4 * vm1[j] + 2 * um1[j] - (j == 1);
            um4[j] = 4 * vm2[j] + 2 * um2[j] - (j == 0);
            vm3[j] = 4 * wm1[j] + 2 * vm1[j] - v1[j];
            vm4[j] = 4 * wm2[j] + 2 * vm2[j] - v0[j];
        }
        for (int j = 0; j < 8; ++j) {
            um5[j] = 4 * vm3[j] + 2 * um3[j] - um1[j];
            um6[j] = 4 * vm4[j] + 2 * um4[j] - um2[j];
        }
        for (int j = 0; j < 8; ++j) {
            g[1][j] = (float)um1[j]; g[2][j] = (float)um2[j]; g[3][j] = (float)um3[j];
            g[4][j] = (float)um4[j]; g[5][j] = (float)um5[j]; g[6][j] = (float)um6[j];
        }
    }
};
constexpr GhostT GH{};

// y-weight table for boundary bands: [ly][parity][ri(14)][k(4)][b(4)]
struct WYTabT {
    float w[2][2][14][4][4];
    constexpr WYTabT() : w{} {
        for (int ly = 0; ly < 2; ++ly)
        for (int gg = 0; gg < 2; ++gg)
        for (int ri = 0; ri < 14; ++ri)
        for (int k = 0; k < 4; ++k) {
            const int r  = ly == 0 ? ri : (H - 14) + ri;
            const int Yo = (ly == 0 ? 0 : H - 8) + gg + 2 * k;
            w[ly][gg][ri][k][0] = (r == Yo) ? 1.f : 0.f;
            w[ly][gg][ri][k][1] = wcoefB(1, Yo, r);
            w[ly][gg][ri][k][2] = wcoefB(2, Yo, r);
            w[ly][gg][ri][k][3] = wcoefB(3, Yo, r);
        }
    }
};
__device__ constexpr WYTabT WYT{};

__device__ __forceinline__ float4 ld4(const float* p) {
    return *reinterpret_cast<const float4*>(p);
}
__device__ __forceinline__ float rfl(float x) {
    return __int_as_float(__builtin_amdgcn_readfirstlane(__float_as_int(x)));
}

struct Uni {
    float k1, k2, k3, m1, m2, n1;                               // x-side M consts
    float wy1a, wy1b, wy2a, wy2b, wy2c, wy3a, wy3b, wy3c, wy3d; // interior y-weights
    float sy1, sy2, sy3;                                        // y powers
    float am, iam;                                              // sigmoid mix, 1/am
};

// Ghost-patch for the 4 edge slots (c in {0,1,126,127}); depth D = 2*CLS.
// rb[8..11] = cols gx0..gx0+3; c==1/126 only need patching at D==6.
template<int D>
__device__ __forceinline__ void patch4(float rb[20], int c) {
    if (c == 0) {
        #pragma unroll
        for (int k = 1; k <= D; ++k) {
            float a = 0.f;
            #pragma unroll
            for (int j = 0; j < 8; ++j) {
                const float w = GH.g[k][j];
                if (w != 0.f) a = fmaf(w, rb[8 + j], a);
            }
            rb[8 - k] = a;
        }
    } else if (D >= 6 && c == 1) {
        #pragma unroll
        for (int k = 1; k <= 2; ++k) {
            float a = 0.f;
            #pragma unroll
            for (int j = 0; j < 8; ++j) {
                const float w = GH.g[k][j];
                if (w != 0.f) a = fmaf(w, rb[4 + j], a);
            }
            rb[4 - k] = a;
        }
    } else if (D >= 6 && c == 126) {
        #pragma unroll
        for (int k = 1; k <= 2; ++k) {
            float a = 0.f;
            #pragma unroll
            for (int j = 0; j < 8; ++j) {
                const float w = GH.g[k][j];
                if (w != 0.f) a = fmaf(w, rb[15 - j], a);
            }
            rb[15 + k] = a;
        }
    } else if (c == 127) {
        #pragma unroll
        for (int k = 1; k <= D; ++k) {
            float a = 0.f;
            #pragma unroll
            for (int j = 0; j < 8; ++j) {
                const float w = GH.g[k][j];
                if (w != 0.f) a = fmaf(w, rb[11 - j], a);
            }
            rb[11 + k] = a;
        }
    }
}

// One trimmed pure-y row. CLS = max x-derivative order needed by this row.
template<int CLS, int RI>
__device__ __forceinline__ void row_pure(const Uni& U, const float* __restrict__ p,
                                         int yb0, const int colm[5], int c,
                                         float acc[4][4]) {
    const int r = yb0 - 6 + 2 * RI;
    const float* row = p + (size_t)r * W;
    float rb[20];
    if (CLS == 0) {
        *reinterpret_cast<float4*>(&rb[8]) = ld4(row + colm[2]);
    } else if (CLS <= 2) {
        *reinterpret_cast<float4*>(&rb[4])  = ld4(row + colm[1]);
        *reinterpret_cast<float4*>(&rb[8])  = ld4(row + colm[2]);
        *reinterpret_cast<float4*>(&rb[12]) = ld4(row + colm[3]);
    } else {
        #pragma unroll
        for (int m = 0; m < 5; ++m)
            *reinterpret_cast<float4*>(&rb[4 * m]) = ld4(row + colm[m]);
    }
    if (CLS >= 1) patch4<2 * CLS>(rb, c);

    #pragma unroll
    for (int j = 0; j < 4; ++j) {
        const float u0 = rb[8 + j];
        const float M3v = 120.f * u0;
        float M2v = 0.f, M1v = 0.f, M0v = 0.f;
        if (CLS >= 1) {
            const float p1 = rb[6 + j] + rb[10 + j];
            const float X1 = fmaf(0.25f, p1, -0.5f * u0);
            M2v = fmaf(U.n1, X1, 45.f * u0);
            if (CLS >= 2) {
                const float p2 = rb[4 + j] + rb[12 + j];
                const float X2 = fmaf(0.0625f, p2, fmaf(-0.25f, p1, 0.375f * u0));
                M1v = fmaf(U.m1, X1, fmaf(U.m2, X2, 10.f * u0));
                if (CLS >= 3) {
                    const float p3 = rb[2 + j] + rb[14 + j];
                    const float X3 = fmaf(1.f/64, p3, fmaf(-6.f/64, p2,
                                      fmaf(15.f/64, p1, (-20.f/64) * u0)));
                    M0v = fmaf(U.k1, X1, fmaf(U.k2, X2, U.k3 * X3));
                }
            }
        }
        #pragma unroll
        for (int k = 0; k < 4; ++k) {
            const int dq = RI - 3 - k;
            const int ad = dq < 0 ? -dq : dq;
            if (ad > 3) continue;
            float a = acc[k][j];
            if (ad == 0) {
                a = fmaf(U.iam, u0, a);       // fold u/am into acc
                a += M0v;
                a = fmaf(U.wy1b, M1v, a);
                a = fmaf(U.wy2c, M2v, a);
                a = fmaf(U.wy3d, M3v, a);
            } else if (ad == 1) {
                a = fmaf(U.wy1a, M1v, a);
                a = fmaf(U.wy2b, M2v, a);
                a = fmaf(U.wy3c, M3v, a);
            } else if (ad == 2) {
                a = fmaf(U.wy2a, M2v, a);
                a = fmaf(U.wy3b, M3v, a);
            } else {
                a = fmaf(U.wy3a, M3v, a);
            }
            acc[k][j] = a;
        }
    }
}

__global__ __launch_bounds__(256) void fused_v9(
        const float* __restrict__ uin, float* __restrict__ outp,
        const float* __restrict__ alpha, const float* __restrict__ beta,
        const float* __restrict__ axp, const float* __restrict__ ayp,
        const float* __restrict__ es) {
    // XCD-chunked swizzle (grid 4096 = 8*512)
    const unsigned bid = blockIdx.x;
    const unsigned swz = (bid & 7u) * (gridDim.x >> 3) + (bid >> 3);
    const unsigned img  = swz >> 6;          // 64 bands of 8 rows per image
    const unsigned band = swz & 63u;

    const float* __restrict__ p = uin + (size_t)img * IMG;
    float* __restrict__ q = outp + (size_t)img * IMG;

    const float sx = 0.01f * alpha[0] * axp[0];
    const float sy = 0.01f * beta[0]  * ayp[0];
    Uni U;
    U.k1 = rfl(10.f * sx);  U.k2 = rfl(45.f * sx * sx);  U.k3 = rfl(120.f * sx * sx * sx);
    U.m1 = rfl(90.f * sx);  U.m2 = rfl(360.f * sx * sx); U.n1 = rfl(360.f * sx);
    const float sy2 = sy * sy, sy3 = sy2 * sy;
    U.sy1 = rfl(sy); U.sy2 = rfl(sy2); U.sy3 = rfl(sy3);
    U.wy1a = rfl(0.25f * sy);    U.wy1b = rfl(-0.5f * sy);
    U.wy2a = rfl(0.0625f * sy2); U.wy2b = rfl(-0.25f * sy2); U.wy2c = rfl(0.375f * sy2);
    U.wy3a = rfl((1.f/64) * sy3);  U.wy3b = rfl((-6.f/64) * sy3);
    U.wy3c = rfl((15.f/64) * sy3); U.wy3d = rfl((-20.f/64) * sy3);
    const float amv = 1.f / (1.f + expf(-es[0]));
    U.am = rfl(amv); U.iam = rfl(1.f / amv);

    const int tid = threadIdx.x;
    const int g = tid >> 7;                      // parity group (2 per block)
    const int c = ((tid & 127) + 2) & 127;       // rotate: edges cluster in odd waves
    const int gx0 = c << 2;

    int colm[5];
    #pragma unroll
    for (int m = 0; m < 5; ++m) {
        int cc = gx0 - 8 + 4 * m;
        colm[m] = cc < 0 ? 0 : (cc > W - 4 ? W - 4 : cc);
    }

    const int y0 = (int)band << 3;
    const int yb0 = y0 + g;                      // outputs at yb0 + 2k
    const bool ytab = (band == 0) || (band == 63);

    float acc[4][4] = {};

    if (!ytab) {
        // ---------- hot path: pure y, class-trimmed rows ----------
        row_pure<0, 0>(U, p, yb0, colm, c, acc);
        row_pure<1, 1>(U, p, yb0, colm, c, acc);
        row_pure<2, 2>(U, p, yb0, colm, c, acc);
        row_pure<3, 3>(U, p, yb0, colm, c, acc);
        row_pure<3, 4>(U, p, yb0, colm, c, acc);
        row_pure<3, 5>(U, p, yb0, colm, c, acc);
        row_pure<3, 6>(U, p, yb0, colm, c, acc);
        row_pure<2, 7>(U, p, yb0, colm, c, acc);
        row_pure<1, 8>(U, p, yb0, colm, c, acc);
        row_pure<0, 9>(U, p, yb0, colm, c, acc);
    } else {
        // ---------- y-boundary bands 0/63 (block-uniform): table path ----------
        const int ly = (band == 0) ? 0 : 1;
        #pragma unroll 1
        for (int ri = 0; ri < 14; ++ri) {
            const int r = ly ? (H - 14) + ri : ri;
            const float* row = p + (size_t)r * W;
            float rb[20];
            #pragma unroll
            for (int m = 0; m < 5; ++m)
                *reinterpret_cast<float4*>(&rb[4 * m]) = ld4(row + colm[m]);
            patch4<6>(rb, c);
            float M0v[4], M1v[4], M2v[4], M3v[4];
            #pragma unroll
            for (int j = 0; j < 4; ++j) {
                const float u0 = rb[8 + j];
                const float p1 = rb[6 + j] + rb[10 + j];
                const float p2 = rb[4 + j] + rb[12 + j];
                const float p3 = rb[2 + j] + rb[14 + j];
                const float X1 = fmaf(0.25f, p1, -0.5f * u0);
                const float X2 = fmaf(0.0625f, p2, fmaf(-0.25f, p1, 0.375f * u0));
                const float X3 = fmaf(1.f/64, p3, fmaf(-6.f/64, p2,
                                  fmaf(15.f/64, p1, (-20.f/64) * u0)));
                // fold u/am into the w0 (r==Yo) term
                M0v[j] = fmaf(U.k1, X1, fmaf(U.k2, X2, fmaf(U.k3, X3, U.iam * u0)));
                M1v[j] = fmaf(U.m1, X1, fmaf(U.m2, X2, 10.f * u0));
                M2v[j] = fmaf(U.n1, X1, 45.f * u0);
                M3v[j] = 120.f * u0;
            }
            #pragma unroll
            for (int k = 0; k < 4; ++k) {
                const float* wr = &WYT.w[ly][g][ri][k][0];
                const float w0 = wr[0];
                const float w1 = wr[1] * U.sy1;
                const float w2 = wr[2] * U.sy2;
                const float w3 = wr[3] * U.sy3;
                #pragma unroll
                for (int j = 0; j < 4; ++j)
                    acc[k][j] = fmaf(w0, M0v[j], fmaf(w1, M1v[j],
                                 fmaf(w2, M2v[j], fmaf(w3, M3v[j], acc[k][j]))));
            }
        }
    }

    // ---- out = am * acc   (acc already contains u/am at the dq==0 row) ----
    #pragma unroll
    for (int k = 0; k < 4; ++k) {
        const int Yo = yb0 + 2 * k;
        float4 o;
        o.x = U.am * acc[k][0];
        o.y = U.am * acc[k][1];
        o.z = U.am * acc[k][2];
        o.w = U.am * acc[k][3];
        *reinterpret_cast<float4*>(q + (size_t)Yo * W + gx0) = o;
    }
}

extern "C" void kernel_launch(void* const* d_in, const int* in_sizes, int n_in,
                              void* d_out, int out_size, void* d_ws, size_t ws_size,
                              hipStream_t stream) {
    const float* u     = (const float*)d_in[0];
    const float* alpha = (const float*)d_in[1];
    const float* beta  = (const float*)d_in[2];
    const float* ax    = (const float*)d_in[3];
    const float* ay    = (const float*)d_in[4];
    const float* es    = (const float*)d_in[5];
    float* out = (float*)d_out;

    int nimg = in_sizes[0] / IMG;            // 64 images
    dim3 block(256);
    dim3 grid((unsigned)(nimg * 64));        // 64 bands (8 rows) per image
    fused_v9<<<grid, block, 0, stream>>>(u, out, alpha, beta, ax, ay, es);
}

// Round 10
// 33.821 us; speedup vs baseline: 7.9428x; 2.2471x over previous
//
#include <hip/hip_runtime.h>
#include <math.h>

#define W 512
#define H 512
#define IMG (W * H)
#define LSTRIDE 84        // LDS row stride in floats
#define LWORDS 6400       // 25 chunks * 256 floats >= 76*84 = 6384

// ---------------- compile-time operator tables ----------------
// 1D composed second-difference D = diff(diff(.)) from the reference.
__host__ __device__ constexpr double dcoefd(int i, int j) {
    if (i == 0) return j == 0 ? 0.5 : j == 1 ? -1.0 : j == 2 ? 0.5 : 0.0;
    if (i == 1) return j == 0 ? 0.5 : j == 1 ? -0.75 : j == 3 ? 0.25 : 0.0;
    return j == i - 2 ? 0.25 : j == i ? -0.5 : j == i + 2 ? 0.25 : 0.0;
}

// Ghost-cell coefficients: u_{-k} = sum_j g[k][j]*u_j makes the PURE stencils
// of D, D^2, D^3 reproduce the boundary-aware operator exactly (validated
// rounds 5-9: absmax identical to explicit-boundary versions).
struct GhostT {
    float g[7][8];
    constexpr GhostT() : g{} {
        double v0[8] = {}, v1[8] = {}, v2[8] = {}, w0[8] = {}, w1r[8] = {}, w2r[8] = {};
        for (int j = 0; j < 8; ++j) { v0[j] = dcoefd(0, j); v1[j] = dcoefd(1, j); v2[j] = dcoefd(2, j); }
        for (int j = 0; j < 8; ++j) {
            double s0 = 0, s1 = 0, s2 = 0;
            for (int k = 0; k < 10; ++k) {
                s0 += dcoefd(0, k) * dcoefd(k, j);
                s1 += dcoefd(1, k) * dcoefd(k, j);
                s2 += dcoefd(2, k) * dcoefd(k, j);
            }
            w0[j] = s0; w1r[j] = s1; w2r[j] = s2;
        }
        double um1[8] = {}, um2[8] = {}, um3[8] = {}, um4[8] = {}, um5[8] = {}, um6[8] = {};
        double vm1[8] = {}, vm2[8] = {}, vm3[8] = {}, vm4[8] = {}, wm1[8] = {}, wm2[8] = {};
        for (int j = 0; j < 8; ++j) {
            um1[j] = 2.0 * (j == 0) - (j == 1);
            um2[j] = 4.0 * (j == 0) - 4.0 * (j == 1) + (j == 2);
            vm1[j] = 2 * v0[j] - v1[j];
            vm2[j] = 4 * v0[j] - 4 * v1[j] + v2[j];
            wm1[j] = 2 * w0[j] - w1r[j];
            wm2[j] = 4 * w0[j] - 4 * w1r[j] + w2r[j];
        }
        for (int j = 0; j < 8; ++j) {
            um3[j] = 4 * vm1[j] + 2 * um1[j] - (j == 1);
            um4[j] = 4 * vm2[j] + 2 * um2[j] - (j == 0);
            vm3[j] = 4 * wm1[j] + 2 * vm1[j] - v1[j];
            vm4[j] = 4 * wm2[j] + 2 * vm2[j] - v0[j];
        }
        for (int j = 0; j < 8; ++j) {
            um5[j] = 4 * vm3[j] + 2 * um3[j] - um1[j];
            um6[j] = 4 * vm4[j] + 2 * um4[j] - um2[j];
        }
        for (int j = 0; j < 8; ++j) {
            g[1][j] = (float)um1[j]; g[2][j] = (float)um2[j]; g[3][j] = (float)um3[j];
            g[4][j] = (float)um4[j]; g[5][j] = (float)um5[j]; g[6][j] = (float)um6[j];
        }
    }
};
constexpr GhostT GH{};

__device__ __forceinline__ float4 ld4(const float* p) {
    return *reinterpret_cast<const float4*>(p);
}
__device__ __forceinline__ float rfl(float x) {
    return __int_as_float(__builtin_amdgcn_readfirstlane(__float_as_int(x)));
}

struct Uni {
    float k1, k2, k3, m1, m2, n1;                               // x-side M consts
    float wy1a, wy1b, wy2a, wy2b, wy2c, wy3a, wy3b, wy3c, wy3d; // interior y-weights
    float am, iam;                                              // sigmoid mix, 1/am
};

// One trimmed pure row read from LDS. CLS = max x-derivative order needed.
// lbase = &lds[y0*LSTRIDE + x0]; rb[i] corresponds to LDS word +i on the row.
template<int CLS, int RI>
__device__ __forceinline__ void row_lds(const Uni& U, const float* __restrict__ lbase,
                                        float acc[4][4]) {
    const float* rowp = lbase + 2 * RI * LSTRIDE;
    float rb[20];
    if (CLS == 0) {
        *reinterpret_cast<float4*>(&rb[8]) = ld4(rowp + 8);
    } else if (CLS <= 2) {
        *reinterpret_cast<float4*>(&rb[4])  = ld4(rowp + 4);
        *reinterpret_cast<float4*>(&rb[8])  = ld4(rowp + 8);
        *reinterpret_cast<float4*>(&rb[12]) = ld4(rowp + 12);
    } else {
        #pragma unroll
        for (int m = 0; m < 5; ++m)
            *reinterpret_cast<float4*>(&rb[4 * m]) = ld4(rowp + 4 * m);
    }

    #pragma unroll
    for (int j = 0; j < 4; ++j) {
        const float u0 = rb[8 + j];
        const float M3v = 120.f * u0;
        float M2v = 0.f, M1v = 0.f, M0v = 0.f;
        if (CLS >= 1) {
            const float p1 = rb[6 + j] + rb[10 + j];
            const float X1 = fmaf(0.25f, p1, -0.5f * u0);
            M2v = fmaf(U.n1, X1, 45.f * u0);
            if (CLS >= 2) {
                const float p2 = rb[4 + j] + rb[12 + j];
                const float X2 = fmaf(0.0625f, p2, fmaf(-0.25f, p1, 0.375f * u0));
                M1v = fmaf(U.m1, X1, fmaf(U.m2, X2, 10.f * u0));
                if (CLS >= 3) {
                    const float p3 = rb[2 + j] + rb[14 + j];
                    const float X3 = fmaf(1.f/64, p3, fmaf(-6.f/64, p2,
                                      fmaf(15.f/64, p1, (-20.f/64) * u0)));
                    M0v = fmaf(U.k1, X1, fmaf(U.k2, X2, U.k3 * X3));
                }
            }
        }
        #pragma unroll
        for (int k = 0; k < 4; ++k) {
            const int dq = RI - 3 - k;
            const int ad = dq < 0 ? -dq : dq;
            if (ad > 3) continue;
            float a = acc[k][j];
            if (ad == 0) {
                a = fmaf(U.iam, u0, a);       // fold u/am into acc
                a += M0v;
                a = fmaf(U.wy1b, M1v, a);
                a = fmaf(U.wy2c, M2v, a);
                a = fmaf(U.wy3d, M3v, a);
            } else if (ad == 1) {
                a = fmaf(U.wy1a, M1v, a);
                a = fmaf(U.wy2b, M2v, a);
                a = fmaf(U.wy3c, M3v, a);
            } else if (ad == 2) {
                a = fmaf(U.wy2a, M2v, a);
                a = fmaf(U.wy3b, M3v, a);
            } else {
                a = fmaf(U.wy3a, M3v, a);
            }
            acc[k][j] = a;
        }
    }
}

__global__ __launch_bounds__(256) void fused_v10(
        const float* __restrict__ uin, float* __restrict__ outp,
        const float* __restrict__ alpha, const float* __restrict__ beta,
        const float* __restrict__ axp, const float* __restrict__ ayp,
        const float* __restrict__ es) {
    __shared__ float lds0[LWORDS];

    // XCD-chunked swizzle (grid 4096 = 8*512)
    const unsigned bid = blockIdx.x;
    const unsigned swz = (bid & 7u) * (gridDim.x >> 3) + (bid >> 3);
    const unsigned img  = swz >> 6;
    const unsigned tile = swz & 63u;
    const int gx0 = (int)(tile & 7u) << 6;
    const int gy0 = (int)(tile >> 3) << 6;
    const float* __restrict__ p = uin + (size_t)img * IMG;
    float* __restrict__ q = outp + (size_t)img * IMG;

    const int tid = threadIdx.x;
    const int wid = tid >> 6, lane = tid & 63;

    // ---- stage u window rows [-6,70) x cols [-8,76) via global_load_lds ----
    // LDS linear: word idx = row*84 + (col+8); chunk t covers words [t*256,(t+1)*256)
    for (int t = wid; t < 25; t += 4) {
        int idx = (t << 8) + (lane << 2);
        int row = (int)((unsigned)idx / 84u);
        if (row > 75) row = 75;
        int col = idx - row * 84;
        int gy = gy0 + row - 6;
        gy = gy < 0 ? 0 : (gy > H - 1 ? H - 1 : gy);
        int gx = gx0 + col - 8;
        gx = gx < 0 ? 0 : (gx > W - 4 ? W - 4 : gx);
        const float* src = p + (size_t)gy * W + gx;
        __builtin_amdgcn_global_load_lds(
            (const __attribute__((address_space(1))) void*)src,
            (__attribute__((address_space(3))) void*)&lds0[t << 8],
            16, 0, 0);
    }
    __syncthreads();

    // ---- y-ghost rows for top/bottom tiles (block-uniform branch) ----
    if (gy0 == 0 || gy0 == H - 64) {
        if (tid < 20) {
            const int w0 = tid << 2;
            float4 r[8];
            if (gy0 == 0) {
                #pragma unroll
                for (int j = 0; j < 8; ++j)
                    r[j] = ld4(&lds0[(6 + j) * LSTRIDE + w0]);
                #pragma unroll
                for (int k = 1; k <= 6; ++k) {
                    float4 a = {0.f, 0.f, 0.f, 0.f};
                    #pragma unroll
                    for (int j = 0; j < 8; ++j) {
                        const float w = GH.g[k][j];
                        if (w != 0.f) {
                            a.x = fmaf(w, r[j].x, a.x); a.y = fmaf(w, r[j].y, a.y);
                            a.z = fmaf(w, r[j].z, a.z); a.w = fmaf(w, r[j].w, a.w);
                        }
                    }
                    *reinterpret_cast<float4*>(&lds0[(6 - k) * LSTRIDE + w0]) = a;
                }
            } else {
                #pragma unroll
                for (int j = 0; j < 8; ++j)
                    r[j] = ld4(&lds0[(69 - j) * LSTRIDE + w0]);
                #pragma unroll
                for (int k = 1; k <= 6; ++k) {
                    float4 a = {0.f, 0.f, 0.f, 0.f};
                    #pragma unroll
                    for (int j = 0; j < 8; ++j) {
                        const float w = GH.g[k][j];
                        if (w != 0.f) {
                            a.x = fmaf(w, r[j].x, a.x); a.y = fmaf(w, r[j].y, a.y);
                            a.z = fmaf(w, r[j].z, a.z); a.w = fmaf(w, r[j].w, a.w);
                        }
                    }
                    *reinterpret_cast<float4*>(&lds0[(69 + k) * LSTRIDE + w0]) = a;
                }
            }
        }
        __syncthreads();
    }

    // ---- x-ghost cols for left/right tiles (runs after y-ghosts: exact) ----
    if (gx0 == 0 || gx0 == W - 64) {
        if (tid < 76) {
            float* rp = &lds0[tid * LSTRIDE];
            float v[8];
            if (gx0 == 0) {
                #pragma unroll
                for (int j = 0; j < 8; ++j) v[j] = rp[8 + j];
                #pragma unroll
                for (int k = 1; k <= 6; ++k) {
                    float s = 0.f;
                    #pragma unroll
                    for (int j = 0; j < 8; ++j) {
                        const float w = GH.g[k][j];
                        if (w != 0.f) s = fmaf(w, v[j], s);
                    }
                    rp[8 - k] = s;
                }
            } else {
                #pragma unroll
                for (int j = 0; j < 8; ++j) v[j] = rp[71 - j];
                #pragma unroll
                for (int k = 1; k <= 6; ++k) {
                    float s = 0.f;
                    #pragma unroll
                    for (int j = 0; j < 8; ++j) {
                        const float w = GH.g[k][j];
                        if (w != 0.f) s = fmaf(w, v[j], s);
                    }
                    rp[71 + k] = s;
                }
            }
        }
        __syncthreads();
    }

    // ---- uniform constants ----
    const float sx = 0.01f * alpha[0] * axp[0];
    const float sy = 0.01f * beta[0]  * ayp[0];
    Uni U;
    U.k1 = rfl(10.f * sx);  U.k2 = rfl(45.f * sx * sx);  U.k3 = rfl(120.f * sx * sx * sx);
    U.m1 = rfl(90.f * sx);  U.m2 = rfl(360.f * sx * sx); U.n1 = rfl(360.f * sx);
    const float sy2 = sy * sy, sy3 = sy2 * sy;
    U.wy1a = rfl(0.25f * sy);    U.wy1b = rfl(-0.5f * sy);
    U.wy2a = rfl(0.0625f * sy2); U.wy2b = rfl(-0.25f * sy2); U.wy2c = rfl(0.375f * sy2);
    U.wy3a = rfl((1.f/64) * sy3);  U.wy3b = rfl((-6.f/64) * sy3);
    U.wy3c = rfl((15.f/64) * sy3); U.wy3d = rfl((-20.f/64) * sy3);
    const float amv = 1.f / (1.f + expf(-es[0]));
    U.am = rfl(amv); U.iam = rfl(1.f / amv);

    // ---- compute: thread = 4-col quad x 4 same-parity rows, branch-free ----
    const int qc = tid & 15, g = tid >> 4;
    const int y0 = ((g >> 1) << 3) + (g & 1);   // tile row of first output
    const int x0 = qc << 2;                     // tile col of quad
    const float* lbase = &lds0[y0 * LSTRIDE + x0];

    float acc[4][4] = {};
    row_lds<0, 0>(U, lbase, acc);
    row_lds<1, 1>(U, lbase, acc);
    row_lds<2, 2>(U, lbase, acc);
    row_lds<3, 3>(U, lbase, acc);
    row_lds<3, 4>(U, lbase, acc);
    row_lds<3, 5>(U, lbase, acc);
    row_lds<3, 6>(U, lbase, acc);
    row_lds<2, 7>(U, lbase, acc);
    row_lds<1, 8>(U, lbase, acc);
    row_lds<0, 9>(U, lbase, acc);

    // ---- out = am * acc  (acc already contains u/am at the dq==0 row) ----
    #pragma unroll
    for (int k = 0; k < 4; ++k) {
        const int Yo = gy0 + y0 + 2 * k;
        float4 o;
        o.x = U.am * acc[k][0];
        o.y = U.am * acc[k][1];
        o.z = U.am * acc[k][2];
        o.w = U.am * acc[k][3];
        *reinterpret_cast<float4*>(q + (size_t)Yo * W + gx0 + x0) = o;
    }
}

extern "C" void kernel_launch(void* const* d_in, const int* in_sizes, int n_in,
                              void* d_out, int out_size, void* d_ws, size_t ws_size,
                              hipStream_t stream) {
    const float* u     = (const float*)d_in[0];
    const float* alpha = (const float*)d_in[1];
    const float* beta  = (const float*)d_in[2];
    const float* ax    = (const float*)d_in[3];
    const float* ay    = (const float*)d_in[4];
    const float* es    = (const float*)d_in[5];
    float* out = (float*)d_out;

    int nimg = in_sizes[0] / IMG;            // 64 images
    dim3 block(256);
    dim3 grid((unsigned)(nimg * 64));        // 8x8 tiles of 64x64 per image
    fused_v10<<<grid, block, 0, stream>>>(u, out, alpha, beta, ax, ay, es);
}